// Round 1
// baseline (364.057 us; speedup 1.0000x reference)
//
#include <hip/hip_runtime.h>

typedef __attribute__((ext_vector_type(8))) short short8;
typedef __attribute__((ext_vector_type(4))) float f32x4;
typedef unsigned short u16;
typedef __attribute__((ext_vector_type(4))) unsigned short u16x4;

#define S_LEN 2048
#define DMODEL 1024
#define NH 16
#define HD 64

static __device__ __forceinline__ u16 f2bf(float f) {
    union { float f; unsigned u; } x; x.f = f;
    unsigned r = x.u + 0x7fffu + ((x.u >> 16) & 1u);
    return (u16)(r >> 16);
}

#define GLD_LDS16(g, l) __builtin_amdgcn_global_load_lds( \
    (const __attribute__((address_space(1))) void*)(g),   \
    (__attribute__((address_space(3))) void*)(l), 16, 0, 0)

// ---------------- cast f32 -> bf16 (vectorized) ----------------
__global__ __launch_bounds__(256) void cast_kernel(const float* __restrict__ in,
                                                   u16* __restrict__ out, int n4) {
    int i = blockIdx.x * 256 + threadIdx.x;
    if (i < n4) {
        const float4 v = reinterpret_cast<const float4*>(in)[i];
        u16x4 o;
        o.x = f2bf(v.x); o.y = f2bf(v.y); o.z = f2bf(v.z); o.w = f2bf(v.w);
        reinterpret_cast<u16x4*>(out)[i] = o;
    }
}

// ---------------- QKV projection GEMM: C = x @ W^T + b ----------------
// A: (4096,1024) bf16 row-major; W: (1024,1024) bf16 row-major (N,K).
// z=0 -> Q (scaled 1/8) into (B,H,S,HD); z=1 -> K same; z=2 -> V transposed (B,H,HD,S).
__global__ __launch_bounds__(256) void gemm_qkv_kernel(
    const u16* __restrict__ xbf,
    const u16* __restrict__ wqbf, const u16* __restrict__ wkbf, const u16* __restrict__ wvbf,
    const float* __restrict__ bq, const float* __restrict__ bk, const float* __restrict__ bv,
    u16* __restrict__ qout, u16* __restrict__ kout, u16* __restrict__ vtout)
{
    __shared__ u16 As[128][64];
    __shared__ u16 Bs[128][64];

    const int z = blockIdx.z;
    const u16* __restrict__ W = (z == 0) ? wqbf : (z == 1) ? wkbf : wvbf;
    const float* __restrict__ bias = (z == 0) ? bq : (z == 1) ? bk : bv;

    const int tid  = threadIdx.x;
    const int lane = tid & 63;
    const int wid  = tid >> 6;
    const int wm = (wid >> 1) * 64;
    const int wn = (wid & 1) * 64;
    const int lr = lane & 15;
    const int lg = lane >> 4;

    const int m0 = blockIdx.y * 128;
    const int n0 = blockIdx.x * 128;

    f32x4 acc[4][4] = {};

    for (int kt = 0; kt < DMODEL; kt += 64) {
#pragma unroll
        for (int i = 0; i < 4; ++i) {
            const int c = i * 256 + tid;
            const int row = c >> 3;
            const int kk = (c & 7) * 8;
            GLD_LDS16(xbf + (size_t)(m0 + row) * DMODEL + kt + kk, &As[0][0] + c * 8);
        }
#pragma unroll
        for (int i = 0; i < 4; ++i) {
            const int c = i * 256 + tid;
            const int row = c >> 3;
            const int kk = (c & 7) * 8;
            GLD_LDS16(W + (size_t)(n0 + row) * DMODEL + kt + kk, &Bs[0][0] + c * 8);
        }
        __syncthreads();
#pragma unroll
        for (int ks = 0; ks < 2; ++ks) {
            short8 af[4], bfr[4];
#pragma unroll
            for (int t = 0; t < 4; ++t)
                af[t] = *(const short8*)&As[wm + t * 16 + lr][ks * 32 + lg * 8];
#pragma unroll
            for (int t = 0; t < 4; ++t)
                bfr[t] = *(const short8*)&Bs[wn + t * 16 + lr][ks * 32 + lg * 8];
#pragma unroll
            for (int mt = 0; mt < 4; ++mt)
#pragma unroll
                for (int nt = 0; nt < 4; ++nt)
                    acc[mt][nt] = __builtin_amdgcn_mfma_f32_16x16x32_bf16(af[mt], bfr[nt], acc[mt][nt], 0, 0, 0);
        }
        __syncthreads();
    }

#pragma unroll
    for (int mt = 0; mt < 4; ++mt) {
#pragma unroll
        for (int nt = 0; nt < 4; ++nt) {
            const int n = n0 + wn + nt * 16 + lr;
            const int h = (n >> 6) & (NH - 1);
            const int hd = n & (HD - 1);
            const float bia = bias[n];
#pragma unroll
            for (int r = 0; r < 4; ++r) {
                const int m = m0 + wm + mt * 16 + lg * 4 + r;
                const int bb = m >> 11;
                const int ss = m & (S_LEN - 1);
                const float v = acc[mt][nt][r] + bia;
                const int bh = bb * NH + h;
                if (z == 0) {
                    qout[((size_t)bh * S_LEN + ss) * HD + hd] = f2bf(v * 0.125f);
                } else if (z == 1) {
                    kout[((size_t)bh * S_LEN + ss) * HD + hd] = f2bf(v);
                } else {
                    vtout[((size_t)bh * HD + hd) * S_LEN + ss] = f2bf(v);
                }
            }
        }
    }
}

// ---------------- flash attention (1 wave per 16 q-rows) ----------------
__global__ __launch_bounds__(64) void attn_kernel(
    const u16* __restrict__ qbf, const u16* __restrict__ kbf,
    const u16* __restrict__ vtbf, const float* __restrict__ rel,
    u16* __restrict__ att)
{
    __shared__ u16 P_lds[16][32];

    const int lane = threadIdx.x;
    const int c = lane & 15;
    const int g = lane >> 4;

    const int bh = blockIdx.y;
    const int b = bh >> 4;
    const int h = bh & (NH - 1);
    const int q0 = blockIdx.x * 16;

    const size_t base = (size_t)bh * S_LEN * HD;

    const short8 qf0 = *(const short8*)&qbf[base + (size_t)(q0 + c) * HD + g * 8];
    const short8 qf1 = *(const short8*)&qbf[base + (size_t)(q0 + c) * HD + 32 + g * 8];

    const float* __restrict__ relh = rel + (size_t)h * S_LEN * S_LEN;

    f32x4 o[4] = {};
    float m_run[4], l_run[4];
#pragma unroll
    for (int r = 0; r < 4; ++r) { m_run[r] = -3e38f; l_run[r] = 0.f; }

    const int nkt = ((q0 + 15) >> 5) + 1;
    for (int kt = 0; kt < nkt; ++kt) {
        const int k0 = kt * 32;
        f32x4 s0 = {}, s1 = {};
        short8 kf;
        kf = *(const short8*)&kbf[base + (size_t)(k0 + c) * HD + g * 8];
        s0 = __builtin_amdgcn_mfma_f32_16x16x32_bf16(qf0, kf, s0, 0, 0, 0);
        kf = *(const short8*)&kbf[base + (size_t)(k0 + c) * HD + 32 + g * 8];
        s0 = __builtin_amdgcn_mfma_f32_16x16x32_bf16(qf1, kf, s0, 0, 0, 0);
        kf = *(const short8*)&kbf[base + (size_t)(k0 + 16 + c) * HD + g * 8];
        s1 = __builtin_amdgcn_mfma_f32_16x16x32_bf16(qf0, kf, s1, 0, 0, 0);
        kf = *(const short8*)&kbf[base + (size_t)(k0 + 16 + c) * HD + 32 + g * 8];
        s1 = __builtin_amdgcn_mfma_f32_16x16x32_bf16(qf1, kf, s1, 0, 0, 0);

        float p0[4], p1[4], tm[4];
#pragma unroll
        for (int r = 0; r < 4; ++r) {
            const int q = q0 + g * 4 + r;
            const int ka = k0 + c, kb2 = k0 + 16 + c;
            float sa = s0[r] + relh[(size_t)q * S_LEN + ka];
            float sb = s1[r] + relh[(size_t)q * S_LEN + kb2];
            if (ka > q) sa = -1e30f;
            if (kb2 > q) sb = -1e30f;
            p0[r] = sa; p1[r] = sb;
            tm[r] = fmaxf(sa, sb);
        }
#pragma unroll
        for (int off = 1; off < 16; off <<= 1)
#pragma unroll
            for (int r = 0; r < 4; ++r)
                tm[r] = fmaxf(tm[r], __shfl_xor(tm[r], off));

        float sc[4];
#pragma unroll
        for (int r = 0; r < 4; ++r) {
            const float mn = fmaxf(m_run[r], tm[r]);
            sc[r] = __expf(m_run[r] - mn);
            m_run[r] = mn;
            p0[r] = __expf(p0[r] - mn);
            p1[r] = __expf(p1[r] - mn);
        }
        float rsum[4];
#pragma unroll
        for (int r = 0; r < 4; ++r) rsum[r] = p0[r] + p1[r];
#pragma unroll
        for (int off = 1; off < 16; off <<= 1)
#pragma unroll
            for (int r = 0; r < 4; ++r)
                rsum[r] += __shfl_xor(rsum[r], off);

#pragma unroll
        for (int r = 0; r < 4; ++r) {
            l_run[r] = l_run[r] * sc[r] + rsum[r];
#pragma unroll
            for (int nt = 0; nt < 4; ++nt) o[nt][r] *= sc[r];
            P_lds[g * 4 + r][c] = f2bf(p0[r]);
            P_lds[g * 4 + r][16 + c] = f2bf(p1[r]);
        }
        __syncthreads();
        const short8 pa = *(const short8*)&P_lds[c][g * 8];
#pragma unroll
        for (int nt = 0; nt < 4; ++nt) {
            const short8 vf = *(const short8*)&vtbf[base + (size_t)(nt * 16 + c) * S_LEN + k0 + g * 8];
            o[nt] = __builtin_amdgcn_mfma_f32_16x16x32_bf16(pa, vf, o[nt], 0, 0, 0);
        }
        __syncthreads();
    }

#pragma unroll
    for (int nt = 0; nt < 4; ++nt)
#pragma unroll
        for (int r = 0; r < 4; ++r) {
            const int q = q0 + g * 4 + r;
            const float v = o[nt][r] / l_run[r];
            att[((size_t)(b * S_LEN + q)) * DMODEL + h * HD + nt * 16 + c] = f2bf(v);
        }
}

// ---------------- O projection GEMM + bias + residual ----------------
__global__ __launch_bounds__(256) void gemm_o_kernel(
    const u16* __restrict__ att, const u16* __restrict__ wobf,
    const float* __restrict__ bo, const float* __restrict__ x,
    float* __restrict__ y)
{
    __shared__ u16 As[128][64];
    __shared__ u16 Bs[128][64];

    const int tid  = threadIdx.x;
    const int lane = tid & 63;
    const int wid  = tid >> 6;
    const int wm = (wid >> 1) * 64;
    const int wn = (wid & 1) * 64;
    const int lr = lane & 15;
    const int lg = lane >> 4;

    const int m0 = blockIdx.y * 128;
    const int n0 = blockIdx.x * 128;

    f32x4 acc[4][4] = {};

    for (int kt = 0; kt < DMODEL; kt += 64) {
#pragma unroll
        for (int i = 0; i < 4; ++i) {
            const int c = i * 256 + tid;
            const int row = c >> 3;
            const int kk = (c & 7) * 8;
            GLD_LDS16(att + (size_t)(m0 + row) * DMODEL + kt + kk, &As[0][0] + c * 8);
        }
#pragma unroll
        for (int i = 0; i < 4; ++i) {
            const int c = i * 256 + tid;
            const int row = c >> 3;
            const int kk = (c & 7) * 8;
            GLD_LDS16(wobf + (size_t)(n0 + row) * DMODEL + kt + kk, &Bs[0][0] + c * 8);
        }
        __syncthreads();
#pragma unroll
        for (int ks = 0; ks < 2; ++ks) {
            short8 af[4], bfr[4];
#pragma unroll
            for (int t = 0; t < 4; ++t)
                af[t] = *(const short8*)&As[wm + t * 16 + lr][ks * 32 + lg * 8];
#pragma unroll
            for (int t = 0; t < 4; ++t)
                bfr[t] = *(const short8*)&Bs[wn + t * 16 + lr][ks * 32 + lg * 8];
#pragma unroll
            for (int mt = 0; mt < 4; ++mt)
#pragma unroll
                for (int nt = 0; nt < 4; ++nt)
                    acc[mt][nt] = __builtin_amdgcn_mfma_f32_16x16x32_bf16(af[mt], bfr[nt], acc[mt][nt], 0, 0, 0);
        }
        __syncthreads();
    }

#pragma unroll
    for (int mt = 0; mt < 4; ++mt) {
#pragma unroll
        for (int nt = 0; nt < 4; ++nt) {
            const int n = n0 + wn + nt * 16 + lr;
            const float bia = bo[n];
#pragma unroll
            for (int r = 0; r < 4; ++r) {
                const int m = m0 + wm + mt * 16 + lg * 4 + r;
                const size_t idx = (size_t)m * DMODEL + n;
                y[idx] = acc[mt][nt][r] + bia + x[idx];
            }
        }
    }
}

// ---------------- LayerNorm ----------------
__global__ __launch_bounds__(256) void ln_kernel(
    const float* __restrict__ y, const float* __restrict__ gamma,
    const float* __restrict__ beta, float* __restrict__ out)
{
    __shared__ float red[8];
    const int row = blockIdx.x;
    const int tid = threadIdx.x;
    const size_t base = (size_t)row * DMODEL + tid * 4;
    const float4 v = *(const float4*)&y[base];
    float s  = v.x + v.y + v.z + v.w;
    float ss = v.x * v.x + v.y * v.y + v.z * v.z + v.w * v.w;
#pragma unroll
    for (int off = 1; off < 64; off <<= 1) {
        s  += __shfl_xor(s, off);
        ss += __shfl_xor(ss, off);
    }
    const int w = tid >> 6;
    if ((tid & 63) == 0) { red[w] = s; red[4 + w] = ss; }
    __syncthreads();
    s  = red[0] + red[1] + red[2] + red[3];
    ss = red[4] + red[5] + red[6] + red[7];
    const float mu = s * (1.0f / DMODEL);
    const float var = ss * (1.0f / DMODEL) - mu * mu;
    const float rstd = rsqrtf(var + 1e-5f);
    const int col = tid * 4;
    float4 o;
    o.x = (v.x - mu) * rstd * gamma[col + 0] + beta[col + 0];
    o.y = (v.y - mu) * rstd * gamma[col + 1] + beta[col + 1];
    o.z = (v.z - mu) * rstd * gamma[col + 2] + beta[col + 2];
    o.w = (v.w - mu) * rstd * gamma[col + 3] + beta[col + 3];
    *(float4*)&out[base] = o;
}

extern "C" void kernel_launch(void* const* d_in, const int* in_sizes, int n_in,
                              void* d_out, int out_size, void* d_ws, size_t ws_size,
                              hipStream_t stream) {
    (void)in_sizes; (void)n_in; (void)out_size; (void)ws_size;
    const float* x     = (const float*)d_in[0];
    const float* Wq    = (const float*)d_in[1];
    const float* bq    = (const float*)d_in[2];
    const float* Wk    = (const float*)d_in[3];
    const float* bk    = (const float*)d_in[4];
    const float* Wv    = (const float*)d_in[5];
    const float* bv    = (const float*)d_in[6];
    const float* Wo    = (const float*)d_in[7];
    const float* bo    = (const float*)d_in[8];
    const float* rel   = (const float*)d_in[9];
    const float* gamma = (const float*)d_in[10];
    const float* beta  = (const float*)d_in[11];
    float* out = (float*)d_out;

    char* ws = (char*)d_ws;
    u16* xbf   = (u16*)(ws);                     //  8 MB (4096x1024 bf16)
    u16* wqbf  = (u16*)(ws + ( 8u << 20));       //  2 MB
    u16* wkbf  = (u16*)(ws + (10u << 20));       //  2 MB
    u16* wvbf  = (u16*)(ws + (12u << 20));       //  2 MB
    u16* wobf  = (u16*)(ws + (14u << 20));       //  2 MB
    u16* qbf   = (u16*)(ws + (16u << 20));       //  8 MB (B,H,S,HD)
    u16* kbf   = (u16*)(ws + (24u << 20));       //  8 MB
    u16* vtbf  = (u16*)(ws + (32u << 20));       //  8 MB (B,H,HD,S)
    u16* attbf = (u16*)(ws + (40u << 20));       //  8 MB (B*S, D)
    float* y   = (float*)(ws + (48u << 20));     // 16 MB

    // casts
    cast_kernel<<<4096, 256, 0, stream>>>(x,  xbf,  (2 * S_LEN * DMODEL) / 4);
    cast_kernel<<<1024, 256, 0, stream>>>(Wq, wqbf, (DMODEL * DMODEL) / 4);
    cast_kernel<<<1024, 256, 0, stream>>>(Wk, wkbf, (DMODEL * DMODEL) / 4);
    cast_kernel<<<1024, 256, 0, stream>>>(Wv, wvbf, (DMODEL * DMODEL) / 4);
    cast_kernel<<<1024, 256, 0, stream>>>(Wo, wobf, (DMODEL * DMODEL) / 4);

    gemm_qkv_kernel<<<dim3(8, 32, 3), 256, 0, stream>>>(
        xbf, wqbf, wkbf, wvbf, bq, bk, bv, qbf, kbf, vtbf);

    attn_kernel<<<dim3(S_LEN / 16, 2 * NH), 64, 0, stream>>>(qbf, kbf, vtbf, rel, attbf);

    gemm_o_kernel<<<dim3(8, 32), 256, 0, stream>>>(attbf, wobf, bo, x, y);

    ln_kernel<<<2 * S_LEN, 256, 0, stream>>>(y, gamma, beta, out);
}